// Round 16
// baseline (49.656 us; speedup 1.0000x reference)
//
#include <hip/hip_runtime.h>
#include <cstddef>
#include <cstdint>

#define NBATCH 32
#define NATOM  128
#define DFEAT  128
#define HDIM   512
#define DOUT   128
#define NTYPE  5
#define NPAIR  25
#define NBOND  32768
#define CAP    1408              // per-type bucket capacity (counts ~1147 +/- 33)
#define TPT    22                // 22*64 = 1408
#define GBLK   550               // 25*22

// output offsets (float elements) for tuple (z, x, t, y, v)
#define OFF_X 4096
#define OFF_T 528384
#define OFF_Y 593920
#define OFF_V 4788224

// k_prep block ranges: out copy (+x_bf fold) | W1 pack | W2 pack | scatter
#define PRE_A 580                // 580*1024 = 593920 exact
#define PRE_C 1600               // W1 pack (25*8*32*64/256)
#define PRE_D 800                // W2 pack (25*16*8*64/256)
#define SCAT  128                // 128*256 = 32768 bonds
#define PREP_BLK (PRE_A+PRE_C+PRE_D+SCAT)

typedef __attribute__((ext_vector_type(8))) short short8;
typedef __attribute__((ext_vector_type(4))) float f32x4;

#define GAS(x) ((__attribute__((address_space(1))) const void*)(x))
#define LAS(x) ((__attribute__((address_space(3))) void*)(x))

__device__ __forceinline__ unsigned short f2bf(float f) {
    unsigned u = __float_as_uint(f);
    u = (u + 0x7FFFu + ((u >> 16) & 1u)) >> 16;
    return (unsigned short)u;
}

// Fused prep: out z/x/t copy (x range also emits x_bf), W1/W2 bf16 fragment
// pack, bond classify/scatter (cursors pre-zeroed by hipMemsetAsync).
// Scatter blocks run CONCURRENTLY with pack blocks (one launch, block ranges).
__global__ __launch_bounds__(256) void k_prep(const int* __restrict__ z,
                                              const float* __restrict__ x,
                                              const int* __restrict__ t,
                                              const float* __restrict__ r,
                                              const float* __restrict__ W1,
                                              const float* __restrict__ W2,
                                              float* __restrict__ out,
                                              short* __restrict__ x_bf,
                                              short* __restrict__ W1p,
                                              short* __restrict__ W2p,
                                              int* __restrict__ cursors,
                                              int* __restrict__ bond_ids) {
    int bid = blockIdx.x, tid = threadIdx.x;
    if (bid < PRE_A) {
        int i4 = (bid * 256 + tid) * 4;
        float4 o;
        if (i4 < OFF_X) {
            const int4 zi = *(const int4*)&z[i4];
            o = make_float4((float)zi.x, (float)zi.y, (float)zi.z, (float)zi.w);
        } else if (i4 < OFF_T) {
            o = *(const float4*)&x[i4 - OFF_X];
            // fold: x -> bf16 pack (read x once)
            short4 s4;
            s4.x = (short)f2bf(o.x); s4.y = (short)f2bf(o.y);
            s4.z = (short)f2bf(o.z); s4.w = (short)f2bf(o.w);
            *(short4*)&x_bf[i4 - OFF_X] = s4;
        } else {
            const int4 ti = *(const int4*)&t[i4 - OFF_T];
            o = make_float4((float)ti.x, (float)ti.y, (float)ti.z, (float)ti.w);
        }
        *(float4*)&out[i4] = o;
    } else if (bid < PRE_A + PRE_C) {
        // W1 [25][256][512] -> idx=((p*8+ks)*32+cf)*64+l ; elem j = W1[p][ks*32+(l>>4)*8+j][cf*16+(l&15)]
        int idx = (bid - PRE_A) * 256 + tid;
        int l  = idx & 63;
        int cf = (idx >> 6) & 31;
        int ks = (idx >> 11) & 7;
        int p  = idx >> 14;
        int col = cf*16 + (l & 15);
        int kb  = ks*32 + (l >> 4)*8;
        const float* src = W1 + ((size_t)p*2*DFEAT + kb)*HDIM + col;
        short8 v;
        #pragma unroll
        for (int j = 0; j < 8; ++j) v[j] = (short)f2bf(src[(size_t)j*HDIM]);
        *((short8*)W1p + idx) = v;
    } else if (bid < PRE_A + PRE_C + PRE_D) {
        // W2 [25][512][128] -> idx=((p*16+ks)*8+cf)*64+l ; elem j = W2[p][ks*32+(l>>4)*8+j][cf*16+(l&15)]
        int idx = (bid - PRE_A - PRE_C) * 256 + tid;
        int l  = idx & 63;
        int cf = (idx >> 6) & 7;
        int ks = (idx >> 9) & 15;
        int p  = idx >> 13;
        int col = cf*16 + (l & 15);
        int kb  = ks*32 + (l >> 4)*8;
        const float* src = W2 + ((size_t)p*HDIM + kb)*DOUT + col;
        short8 v;
        #pragma unroll
        for (int j = 0; j < 8; ++j) v[j] = (short)f2bf(src[(size_t)j*DOUT]);
        *((short8*)W2p + idx) = v;
    } else {
        // scatter: per-bond classify + v + bucket + zero invalid y rows
        __shared__ int hist[NPAIR];
        __shared__ int base[NPAIR];
        if (tid < NPAIR) hist[tid] = 0;
        __syncthreads();
        int i = (bid - PRE_A - PRE_C - PRE_D) * 256 + tid;
        int b = i >> 10;
        int t1 = t[2*i], t2 = t[2*i+1];
        float vx = 0.f, vy = 0.f, vz = 0.f;
        int p = -1, rk = 0;
        if (t1 != -1) {
            int g1 = b*NATOM + t1, g2 = b*NATOM + t2;
            p = z[g1]*NTYPE + z[g2];
            rk = atomicAdd(&hist[p], 1);
            float dx = r[3*g2+0]-r[3*g1+0];
            float dy = r[3*g2+1]-r[3*g1+1];
            float dz = r[3*g2+2]-r[3*g1+2];
            float n2 = fmaxf(dx*dx+dy*dy+dz*dz, 1e-24f);
            float inv = 1.0f / sqrtf(n2);
            vx = dx*inv; vy = dy*inv; vz = dz*inv;
        } else {
            float4 zr = make_float4(0.f, 0.f, 0.f, 0.f);
            float4* yp = (float4*)&out[OFF_Y + (size_t)i * DOUT];
            #pragma unroll
            for (int c2 = 0; c2 < DOUT/4; ++c2) yp[c2] = zr;
        }
        float* out_v = out + OFF_V;
        out_v[3*i+0] = vx; out_v[3*i+1] = vy; out_v[3*i+2] = vz;
        __syncthreads();
        if (tid < NPAIR) base[tid] = atomicAdd(&cursors[tid], hist[tid]);
        __syncthreads();
        if (p >= 0) {
            int pos = base[p] + rk;
            if (pos < CAP) bond_ids[p*CAP + pos] = i;
        }
    }
}

// Stage (cc,rr) of the flat 48-stage schedule into wbuf parity rr%3.
// rr may be chunk-relative +2 lookahead (wraps into next chunk / dummy wrap at end).
#define STAGE(cc_, rr_) do { \
    int _c = (cc_), _r = (rr_); \
    if (_r >= 12) { _r -= 12; _c += 1; if (_c >= 4) _c = 0; } \
    const char* _s; \
    if (_r < 8) _s = (const char*)W1p + (((size_t)(p*8 + _r)*32 + _c*8 + wc*2)*64 + l)*16; \
    else        _s = (const char*)W2p + (((size_t)(p*16 + _c*4 + (_r-8))*8 + wc*2)*64 + l)*16; \
    char* _d = (char*)wbuf + ((rr_)%3)*8192 + wc*2048 + l*16; \
    __builtin_amdgcn_global_load_lds(GAS(_s), LAS(_d), 16, 0, 0); \
    __builtin_amdgcn_global_load_lds(GAS(_s+1024), LAS(_d+1024), 16, 0, 0); \
} while(0)

// Fused grouped GEMM. Block = (type, 64 bonds). 4 waves, col-split 1x4.
// Prologue: cooperative L2 prewarm of the type's packed weights. Loop: 3-deep
// per-wave DMA pipeline, vmcnt(4), a-frags read before the wait. (R9 optimum,
// byte-identical.)
__global__ __launch_bounds__(256, 2) void k_gemm(const short* __restrict__ x_bf,
                                                 const int* __restrict__ t,
                                                 const short* __restrict__ W1p,
                                                 const float* __restrict__ b1,
                                                 const short* __restrict__ W2p,
                                                 const float* __restrict__ b2,
                                                 const int* __restrict__ cursors,
                                                 const int* __restrict__ bond_ids,
                                                 float* __restrict__ y_out) {
    // bijective XCD remap for nwg=550: q=68, r=6 (same-type blocks stay on one XCD)
    int orig = blockIdx.x;
    int xcd = orig & 7, ib = orig >> 3;
    int wk = (xcd < 6 ? xcd*69 : 414 + (xcd-6)*68) + ib;
    int p = wk / TPT, tileIdx = wk % TPT;
    int cnt = min(cursors[p], CAP);
    if (tileIdx*64 >= cnt) return;
    int nb = min(64, cnt - tileIdx*64);
    int ntiles = (cnt + 63) >> 6;

    __shared__ short xs[64*256];     // 32 KB, swizzled
    __shared__ short hs[64*128];     // 16 KB, swizzled
    __shared__ char  wbuf[3*8192];   // 24 KB weight 3-buffer (per-wave 2KB regions)
    __shared__ float b1s[HDIM];
    __shared__ float b2s[DOUT];
    __shared__ int   srow[64][2];
    __shared__ int   sb[64];

    int tid = threadIdx.x;
    int l = tid & 63, wc = tid >> 6;
    int lr = l & 15, lq = l >> 4;
    int klq = lq * 16;

    if (tid < 64) {
        int bi = (tid < nb) ? bond_ids[p*CAP + tileIdx*64 + tid] : -1;
        sb[tid] = bi;
        int r0 = 0, r1 = 0;
        if (bi >= 0) { int b = bi >> 10; r0 = b*NATOM + t[2*bi]; r1 = b*NATOM + t[2*bi+1]; }
        srow[tid][0] = r0; srow[tid][1] = r1;
    }

    // ---- cooperative L2 prewarm: this block's 1/ntiles slice of W1p+W2p(type)
    {
        float snk = 0.f;
        const char* w1t = (const char*)W1p + (size_t)p*262144;
        int o1 = (int)(((long)tileIdx * 262144) / ntiles) & ~63;
        int e1 = (int)(((long)(tileIdx+1) * 262144) / ntiles);
        for (int o = o1 + tid*16; o < e1; o += 4096) {
            float4 v = *(const float4*)(w1t + o);
            snk += v.x + v.y + v.z + v.w;
        }
        const char* w2t = (const char*)W2p + (size_t)p*131072;
        int o2 = (int)(((long)tileIdx * 131072) / ntiles) & ~63;
        int e2 = (int)(((long)(tileIdx+1) * 131072) / ntiles);
        for (int o = o2 + tid*16; o < e2; o += 4096) {
            float4 v = *(const float4*)(w2t + o);
            snk += v.x + v.y + v.z + v.w;
        }
        asm volatile("" :: "v"(snk));   // rule #17: keep prewarm loads live
    }

    if (tid < 128)
        __builtin_amdgcn_global_load_lds(GAS((const char*)(b1 + (size_t)p*HDIM) + tid*16),
                                         LAS((char*)b1s + tid*16), 16, 0, 0);
    if (tid < 32)
        __builtin_amdgcn_global_load_lds(GAS((const char*)(b2 + (size_t)p*DOUT) + tid*16),
                                         LAS((char*)b2s + tid*16), 16, 0, 0);
    STAGE(0, 0);
    STAGE(0, 1);
    __syncthreads();   // srow visible; drains prewarm + stage0/1 + bias DMAs

    // gather x_c via global_load_lds: linear LDS dest, inverse-swizzled per-lane source
    #pragma unroll
    for (int j = 0; j < 8; ++j) {
        int o = j*4096 + tid*16;
        int row = o >> 9;
        int c16 = ((o >> 4) & 31) ^ (row & 7);
        const char* src = (const char*)x_bf + ((size_t)srow[row][c16 >> 4]*DFEAT + (c16 & 15)*8)*2;
        __builtin_amdgcn_global_load_lds(GAS(src), LAS((char*)xs + o), 16, 0, 0);
    }
    __syncthreads();   // xs resident; vmcnt drained -> in-loop vmcnt counts only stages

    f32x4 yacc[4][2] = {};

    for (int c = 0; c < 4; ++c) {
        float b1c0 = b1s[c*128 + wc*32 + lr];
        float b1c1 = b1s[c*128 + wc*32 + 16 + lr];
        f32x4 acc1[4][2] = {};
        #pragma unroll
        for (int r = 0; r < 8; ++r) {
            short8 a0, a1, a2, a3;   // a-frags read BEFORE the vmcnt wait
            {
                const char* xb = (const char*)xs;
                a0 = *(const short8*)(xb + (0*16+lr)*512 + ((r*64 + klq) ^ (((0*16+lr)&7) << 4)));
                a1 = *(const short8*)(xb + (1*16+lr)*512 + ((r*64 + klq) ^ (((1*16+lr)&7) << 4)));
                a2 = *(const short8*)(xb + (2*16+lr)*512 + ((r*64 + klq) ^ (((2*16+lr)&7) << 4)));
                a3 = *(const short8*)(xb + (3*16+lr)*512 + ((r*64 + klq) ^ (((3*16+lr)&7) << 4)));
            }
            STAGE(c, r + 2);
            asm volatile("s_waitcnt vmcnt(4)" ::: "memory");
            const char* wb = (const char*)wbuf + (r%3)*8192 + wc*2048 + l*16;
            short8 w0 = *(const short8*)wb;
            short8 w1 = *(const short8*)(wb + 1024);
            __builtin_amdgcn_s_setprio(1);
            acc1[0][0] = __builtin_amdgcn_mfma_f32_16x16x32_bf16(a0, w0, acc1[0][0], 0, 0, 0);
            acc1[0][1] = __builtin_amdgcn_mfma_f32_16x16x32_bf16(a0, w1, acc1[0][1], 0, 0, 0);
            acc1[1][0] = __builtin_amdgcn_mfma_f32_16x16x32_bf16(a1, w0, acc1[1][0], 0, 0, 0);
            acc1[1][1] = __builtin_amdgcn_mfma_f32_16x16x32_bf16(a1, w1, acc1[1][1], 0, 0, 0);
            acc1[2][0] = __builtin_amdgcn_mfma_f32_16x16x32_bf16(a2, w0, acc1[2][0], 0, 0, 0);
            acc1[2][1] = __builtin_amdgcn_mfma_f32_16x16x32_bf16(a2, w1, acc1[2][1], 0, 0, 0);
            acc1[3][0] = __builtin_amdgcn_mfma_f32_16x16x32_bf16(a3, w0, acc1[3][0], 0, 0, 0);
            acc1[3][1] = __builtin_amdgcn_mfma_f32_16x16x32_bf16(a3, w1, acc1[3][1], 0, 0, 0);
            __builtin_amdgcn_s_setprio(0);
        }
        // bias + silu -> hs (bf16, swizzled). D layout: col=l&15, row=(l>>4)*4+reg
        #pragma unroll
        for (int rf = 0; rf < 4; ++rf) {
            #pragma unroll
            for (int cf = 0; cf < 2; ++cf) {
                int colb = (wc*32 + cf*16 + lr) * 2;
                float bb = cf ? b1c1 : b1c0;
                #pragma unroll
                for (int reg = 0; reg < 4; ++reg) {
                    int row = rf*16 + lq*4 + reg;
                    float sv = acc1[rf][cf][reg] + bb;
                    float hv = sv / (1.0f + __expf(-sv));
                    *(unsigned short*)((char*)hs + row*256 + (colb ^ ((row & 7) << 4))) = f2bf(hv);
                }
            }
        }
        asm volatile("s_waitcnt lgkmcnt(0)" ::: "memory");
        __builtin_amdgcn_s_barrier();          // hs ready; weight DMAs stay in flight

        #pragma unroll
        for (int r2 = 8; r2 < 12; ++r2) {
            short8 a0, a1, a2, a3;
            {
                const char* hb = (const char*)hs;
                int s2 = r2 - 8;
                a0 = *(const short8*)(hb + (0*16+lr)*256 + ((s2*64 + klq) ^ (((0*16+lr)&7) << 4)));
                a1 = *(const short8*)(hb + (1*16+lr)*256 + ((s2*64 + klq) ^ (((1*16+lr)&7) << 4)));
                a2 = *(const short8*)(hb + (2*16+lr)*256 + ((s2*64 + klq) ^ (((2*16+lr)&7) << 4)));
                a3 = *(const short8*)(hb + (3*16+lr)*256 + ((s2*64 + klq) ^ (((3*16+lr)&7) << 4)));
            }
            STAGE(c, r2 + 2);
            asm volatile("s_waitcnt vmcnt(4)" ::: "memory");
            const char* wb = (const char*)wbuf + (r2%3)*8192 + wc*2048 + l*16;
            short8 w0 = *(const short8*)wb;
            short8 w1 = *(const short8*)(wb + 1024);
            __builtin_amdgcn_s_setprio(1);
            yacc[0][0] = __builtin_amdgcn_mfma_f32_16x16x32_bf16(a0, w0, yacc[0][0], 0, 0, 0);
            yacc[0][1] = __builtin_amdgcn_mfma_f32_16x16x32_bf16(a0, w1, yacc[0][1], 0, 0, 0);
            yacc[1][0] = __builtin_amdgcn_mfma_f32_16x16x32_bf16(a1, w0, yacc[1][0], 0, 0, 0);
            yacc[1][1] = __builtin_amdgcn_mfma_f32_16x16x32_bf16(a1, w1, yacc[1][1], 0, 0, 0);
            yacc[2][0] = __builtin_amdgcn_mfma_f32_16x16x32_bf16(a2, w0, yacc[2][0], 0, 0, 0);
            yacc[2][1] = __builtin_amdgcn_mfma_f32_16x16x32_bf16(a2, w1, yacc[2][1], 0, 0, 0);
            yacc[3][0] = __builtin_amdgcn_mfma_f32_16x16x32_bf16(a3, w0, yacc[3][0], 0, 0, 0);
            yacc[3][1] = __builtin_amdgcn_mfma_f32_16x16x32_bf16(a3, w1, yacc[3][1], 0, 0, 0);
            __builtin_amdgcn_s_setprio(0);
        }
        if (c < 3) {   // hs reads done block-wide before next chunk overwrites
            asm volatile("s_waitcnt lgkmcnt(0)" ::: "memory");
            __builtin_amdgcn_s_barrier();
        }
    }

    // epilogue: y = yacc + b2 for valid rows
    float bo0 = b2s[wc*32 + lr], bo1 = b2s[wc*32 + 16 + lr];
    #pragma unroll
    for (int rf = 0; rf < 4; ++rf) {
        #pragma unroll
        for (int cf = 0; cf < 2; ++cf) {
            int col = wc*32 + cf*16 + lr;
            float bo = cf ? bo1 : bo0;
            #pragma unroll
            for (int reg = 0; reg < 4; ++reg) {
                int row = rf*16 + lq*4 + reg;
                if (row < nb)
                    y_out[(size_t)sb[row]*DOUT + col] = yacc[rf][cf][reg] + bo;
            }
        }
    }
}

extern "C" void kernel_launch(void* const* d_in, const int* in_sizes, int n_in,
                              void* d_out, int out_size, void* d_ws, size_t ws_size,
                              hipStream_t stream) {
    const int*   z  = (const int*)  d_in[0];
    const float* r  = (const float*)d_in[1];
    const float* x  = (const float*)d_in[2];
    const int*   t  = (const int*)  d_in[3];
    const float* W1 = (const float*)d_in[4];
    const float* b1 = (const float*)d_in[5];
    const float* W2 = (const float*)d_in[6];
    const float* b2 = (const float*)d_in[7];
    float* out = (float*)d_out;

    char* ws = (char*)d_ws;
    int*   cursors  = (int*)(ws);                 // 256 B
    int*   bond_ids = (int*)(ws + 256);           // 25*1408*4 = 140800 B
    short* x_bf     = (short*)(ws + 141312);      // 1 MB
    short* W1p      = (short*)(ws + 1189888);     // 6.25 MB
    short* W2p      = (short*)(ws + 7743488);     // 3.125 MB

    hipMemsetAsync(cursors, 0, 128, stream);
    k_prep<<<PREP_BLK, 256, 0, stream>>>(z, x, t, r, W1, W2, out, x_bf, W1p, W2p, cursors, bond_ids);
    k_gemm<<<GBLK, 256, 0, stream>>>(x_bf, t, W1p, b1, W2p, b2, cursors, bond_ids, out + OFF_Y);
}

// Round 17
// 45.619 us; speedup vs baseline: 1.0885x; 1.0885x over previous
//
#include <hip/hip_runtime.h>
#include <cstddef>
#include <cstdint>

#define NBATCH 32
#define NATOM  128
#define DFEAT  128
#define HDIM   512
#define DOUT   128
#define NTYPE  5
#define NPAIR  25
#define NBOND  32768
#define CAP    1408              // per-type bucket capacity (counts ~1147 +/- 33)
#define TPT    22                // 22*64 = 1408
#define GBLK   550               // 25*22

// output offsets (float elements) for tuple (z, x, t, y, v)
#define OFF_X 4096
#define OFF_T 528384
#define OFF_Y 593920
#define OFF_V 4788224

// k_pre block ranges
#define PRE_A 580                // out copy (z,x,t) float4  (580*1024 = 593920 exact)
#define PRE_B 256                // x -> bf16 pack
#define PRE_C 1600               // W1 pack
#define PRE_D 800                // W2 pack
#define PRE_BLK (PRE_A+PRE_B+PRE_C+PRE_D)

typedef __attribute__((ext_vector_type(8))) short short8;
typedef __attribute__((ext_vector_type(4))) float f32x4;

#define GAS(x) ((__attribute__((address_space(1))) const void*)(x))
#define LAS(x) ((__attribute__((address_space(3))) void*)(x))

__device__ __forceinline__ unsigned short f2bf(float f) {
    unsigned u = __float_as_uint(f);
    u = (u + 0x7FFFu + ((u >> 16) & 1u)) >> 16;
    return (unsigned short)u;
}

// Fused prep: out z/x/t copy, x->bf16, W1/W2 bf16 fragment pack, cursor init.
__global__ __launch_bounds__(256) void k_pre(const int* __restrict__ z,
                                             const float* __restrict__ x,
                                             const int* __restrict__ t,
                                             const float* __restrict__ W1,
                                             const float* __restrict__ W2,
                                             float* __restrict__ out,
                                             short* __restrict__ x_bf,
                                             short* __restrict__ W1p,
                                             short* __restrict__ W2p,
                                             int* __restrict__ cursors) {
    int bid = blockIdx.x, tid = threadIdx.x;
    if (bid == 0 && tid < 32) cursors[tid] = 0;
    if (bid < PRE_A) {
        int i4 = (bid * 256 + tid) * 4;
        float4 o;
        if (i4 < OFF_X) {
            const int4 zi = *(const int4*)&z[i4];
            o = make_float4((float)zi.x, (float)zi.y, (float)zi.z, (float)zi.w);
        } else if (i4 < OFF_T) {
            o = *(const float4*)&x[i4 - OFF_X];
        } else {
            const int4 ti = *(const int4*)&t[i4 - OFF_T];
            o = make_float4((float)ti.x, (float)ti.y, (float)ti.z, (float)ti.w);
        }
        *(float4*)&out[i4] = o;
    } else if (bid < PRE_A + PRE_B) {
        int idx = (bid - PRE_A) * 256 + tid;
        const float4* px = (const float4*)&x[idx * 8];
        float4 fa = px[0], fb = px[1];
        short8 v;
        v[0]=(short)f2bf(fa.x); v[1]=(short)f2bf(fa.y); v[2]=(short)f2bf(fa.z); v[3]=(short)f2bf(fa.w);
        v[4]=(short)f2bf(fb.x); v[5]=(short)f2bf(fb.y); v[6]=(short)f2bf(fb.z); v[7]=(short)f2bf(fb.w);
        *((short8*)x_bf + idx) = v;
    } else if (bid < PRE_A + PRE_B + PRE_C) {
        // W1 [25][256][512] -> idx=((p*8+ks)*32+cf)*64+l ; elem j = W1[p][ks*32+(l>>4)*8+j][cf*16+(l&15)]
        int idx = (bid - PRE_A - PRE_B) * 256 + tid;
        int l  = idx & 63;
        int cf = (idx >> 6) & 31;
        int ks = (idx >> 11) & 7;
        int p  = idx >> 14;
        int col = cf*16 + (l & 15);
        int kb  = ks*32 + (l >> 4)*8;
        const float* src = W1 + ((size_t)p*2*DFEAT + kb)*HDIM + col;
        short8 v;
        #pragma unroll
        for (int j = 0; j < 8; ++j) v[j] = (short)f2bf(src[(size_t)j*HDIM]);
        *((short8*)W1p + idx) = v;
    } else {
        // W2 [25][512][128] -> idx=((p*16+ks)*8+cf)*64+l ; elem j = W2[p][ks*32+(l>>4)*8+j][cf*16+(l&15)]
        int idx = (bid - PRE_A - PRE_B - PRE_C) * 256 + tid;
        int l  = idx & 63;
        int cf = (idx >> 6) & 7;
        int ks = (idx >> 9) & 15;
        int p  = idx >> 13;
        int col = cf*16 + (l & 15);
        int kb  = ks*32 + (l >> 4)*8;
        const float* src = W2 + ((size_t)p*HDIM + kb)*DOUT + col;
        short8 v;
        #pragma unroll
        for (int j = 0; j < 8; ++j) v[j] = (short)f2bf(src[(size_t)j*DOUT]);
        *((short8*)W2p + idx) = v;
    }
}

// per-bond classify + v output + bucket scatter + zero y rows of invalid bonds
__global__ __launch_bounds__(256) void k_scatter(const int* __restrict__ z,
                                                 const float* __restrict__ r,
                                                 const int* __restrict__ t,
                                                 float* __restrict__ out_v,
                                                 float* __restrict__ y_out,
                                                 int* __restrict__ cursors,
                                                 int* __restrict__ bond_ids) {
    __shared__ int hist[NPAIR];
    __shared__ int base[NPAIR];
    int tid = threadIdx.x;
    if (tid < NPAIR) hist[tid] = 0;
    __syncthreads();

    int i = blockIdx.x * 256 + tid;
    int b = i >> 10;
    int t1 = t[2*i], t2 = t[2*i+1];
    float vx = 0.f, vy = 0.f, vz = 0.f;
    int p = -1, rk = 0;
    if (t1 != -1) {
        int g1 = b*NATOM + t1, g2 = b*NATOM + t2;
        p = z[g1]*NTYPE + z[g2];
        rk = atomicAdd(&hist[p], 1);
        float dx = r[3*g2+0]-r[3*g1+0];
        float dy = r[3*g2+1]-r[3*g1+1];
        float dz = r[3*g2+2]-r[3*g1+2];
        float n2 = fmaxf(dx*dx+dy*dy+dz*dz, 1e-24f);
        float inv = 1.0f / sqrtf(n2);
        vx = dx*inv; vy = dy*inv; vz = dz*inv;
    } else {
        float4 zr = make_float4(0.f, 0.f, 0.f, 0.f);
        float4* yp = (float4*)&y_out[(size_t)i * DOUT];
        #pragma unroll
        for (int c = 0; c < DOUT/4; ++c) yp[c] = zr;
    }
    out_v[3*i+0] = vx; out_v[3*i+1] = vy; out_v[3*i+2] = vz;
    __syncthreads();
    if (tid < NPAIR) base[tid] = atomicAdd(&cursors[tid], hist[tid]);
    __syncthreads();
    if (p >= 0) {
        int pos = base[p] + rk;
        if (pos < CAP) bond_ids[p*CAP + pos] = i;
    }
}

// Stage (cc,rr) of the flat 48-stage schedule into wbuf parity rr%3.
// rr may be chunk-relative +2 lookahead (wraps into next chunk / dummy wrap at end).
#define STAGE(cc_, rr_) do { \
    int _c = (cc_), _r = (rr_); \
    if (_r >= 12) { _r -= 12; _c += 1; if (_c >= 4) _c = 0; } \
    const char* _s; \
    if (_r < 8) _s = (const char*)W1p + (((size_t)(p*8 + _r)*32 + _c*8 + wc*2)*64 + l)*16; \
    else        _s = (const char*)W2p + (((size_t)(p*16 + _c*4 + (_r-8))*8 + wc*2)*64 + l)*16; \
    char* _d = (char*)wbuf + ((rr_)%3)*8192 + wc*2048 + l*16; \
    __builtin_amdgcn_global_load_lds(GAS(_s), LAS(_d), 16, 0, 0); \
    __builtin_amdgcn_global_load_lds(GAS(_s+1024), LAS(_d+1024), 16, 0, 0); \
} while(0)

// Fused grouped GEMM. Block = (type, 64 bonds). 4 waves, col-split 1x4.
// Prologue: cooperative L2 prewarm of the type's packed weights. Loop: 3-deep
// per-wave DMA pipeline, vmcnt(4), a-frags read before the wait. (R9 optimum.)
__global__ __launch_bounds__(256, 2) void k_gemm(const short* __restrict__ x_bf,
                                                 const int* __restrict__ t,
                                                 const short* __restrict__ W1p,
                                                 const float* __restrict__ b1,
                                                 const short* __restrict__ W2p,
                                                 const float* __restrict__ b2,
                                                 const int* __restrict__ cursors,
                                                 const int* __restrict__ bond_ids,
                                                 float* __restrict__ y_out) {
    // bijective XCD remap for nwg=550: q=68, r=6 (same-type blocks stay on one XCD)
    int orig = blockIdx.x;
    int xcd = orig & 7, ib = orig >> 3;
    int wk = (xcd < 6 ? xcd*69 : 414 + (xcd-6)*68) + ib;
    int p = wk / TPT, tileIdx = wk % TPT;
    int cnt = min(cursors[p], CAP);
    if (tileIdx*64 >= cnt) return;
    int nb = min(64, cnt - tileIdx*64);
    int ntiles = (cnt + 63) >> 6;

    __shared__ short xs[64*256];     // 32 KB, swizzled
    __shared__ short hs[64*128];     // 16 KB, swizzled
    __shared__ char  wbuf[3*8192];   // 24 KB weight 3-buffer (per-wave 2KB regions)
    __shared__ float b1s[HDIM];
    __shared__ float b2s[DOUT];
    __shared__ int   srow[64][2];
    __shared__ int   sb[64];

    int tid = threadIdx.x;
    int l = tid & 63, wc = tid >> 6;
    int lr = l & 15, lq = l >> 4;
    int klq = lq * 16;

    if (tid < 64) {
        int bi = (tid < nb) ? bond_ids[p*CAP + tileIdx*64 + tid] : -1;
        sb[tid] = bi;
        int r0 = 0, r1 = 0;
        if (bi >= 0) { int b = bi >> 10; r0 = b*NATOM + t[2*bi]; r1 = b*NATOM + t[2*bi+1]; }
        srow[tid][0] = r0; srow[tid][1] = r1;
    }

    // ---- cooperative L2 prewarm: this block's 1/ntiles slice of W1p+W2p(type)
    {
        float snk = 0.f;
        const char* w1t = (const char*)W1p + (size_t)p*262144;
        int o1 = (int)(((long)tileIdx * 262144) / ntiles) & ~63;
        int e1 = (int)(((long)(tileIdx+1) * 262144) / ntiles);
        for (int o = o1 + tid*16; o < e1; o += 4096) {
            float4 v = *(const float4*)(w1t + o);
            snk += v.x + v.y + v.z + v.w;
        }
        const char* w2t = (const char*)W2p + (size_t)p*131072;
        int o2 = (int)(((long)tileIdx * 131072) / ntiles) & ~63;
        int e2 = (int)(((long)(tileIdx+1) * 131072) / ntiles);
        for (int o = o2 + tid*16; o < e2; o += 4096) {
            float4 v = *(const float4*)(w2t + o);
            snk += v.x + v.y + v.z + v.w;
        }
        asm volatile("" :: "v"(snk));   // rule #17: keep prewarm loads live
    }

    if (tid < 128)
        __builtin_amdgcn_global_load_lds(GAS((const char*)(b1 + (size_t)p*HDIM) + tid*16),
                                         LAS((char*)b1s + tid*16), 16, 0, 0);
    if (tid < 32)
        __builtin_amdgcn_global_load_lds(GAS((const char*)(b2 + (size_t)p*DOUT) + tid*16),
                                         LAS((char*)b2s + tid*16), 16, 0, 0);
    STAGE(0, 0);
    STAGE(0, 1);
    __syncthreads();   // srow visible; drains prewarm + stage0/1 + bias DMAs

    // gather x_c via global_load_lds: linear LDS dest, inverse-swizzled per-lane source
    #pragma unroll
    for (int j = 0; j < 8; ++j) {
        int o = j*4096 + tid*16;
        int row = o >> 9;
        int c16 = ((o >> 4) & 31) ^ (row & 7);
        const char* src = (const char*)x_bf + ((size_t)srow[row][c16 >> 4]*DFEAT + (c16 & 15)*8)*2;
        __builtin_amdgcn_global_load_lds(GAS(src), LAS((char*)xs + o), 16, 0, 0);
    }
    __syncthreads();   // xs resident; vmcnt drained -> in-loop vmcnt counts only stages

    f32x4 yacc[4][2] = {};

    for (int c = 0; c < 4; ++c) {
        float b1c0 = b1s[c*128 + wc*32 + lr];
        float b1c1 = b1s[c*128 + wc*32 + 16 + lr];
        f32x4 acc1[4][2] = {};
        #pragma unroll
        for (int r = 0; r < 8; ++r) {
            short8 a0, a1, a2, a3;   // a-frags read BEFORE the vmcnt wait
            {
                const char* xb = (const char*)xs;
                a0 = *(const short8*)(xb + (0*16+lr)*512 + ((r*64 + klq) ^ (((0*16+lr)&7) << 4)));
                a1 = *(const short8*)(xb + (1*16+lr)*512 + ((r*64 + klq) ^ (((1*16+lr)&7) << 4)));
                a2 = *(const short8*)(xb + (2*16+lr)*512 + ((r*64 + klq) ^ (((2*16+lr)&7) << 4)));
                a3 = *(const short8*)(xb + (3*16+lr)*512 + ((r*64 + klq) ^ (((3*16+lr)&7) << 4)));
            }
            STAGE(c, r + 2);
            asm volatile("s_waitcnt vmcnt(4)" ::: "memory");
            const char* wb = (const char*)wbuf + (r%3)*8192 + wc*2048 + l*16;
            short8 w0 = *(const short8*)wb;
            short8 w1 = *(const short8*)(wb + 1024);
            __builtin_amdgcn_s_setprio(1);
            acc1[0][0] = __builtin_amdgcn_mfma_f32_16x16x32_bf16(a0, w0, acc1[0][0], 0, 0, 0);
            acc1[0][1] = __builtin_amdgcn_mfma_f32_16x16x32_bf16(a0, w1, acc1[0][1], 0, 0, 0);
            acc1[1][0] = __builtin_amdgcn_mfma_f32_16x16x32_bf16(a1, w0, acc1[1][0], 0, 0, 0);
            acc1[1][1] = __builtin_amdgcn_mfma_f32_16x16x32_bf16(a1, w1, acc1[1][1], 0, 0, 0);
            acc1[2][0] = __builtin_amdgcn_mfma_f32_16x16x32_bf16(a2, w0, acc1[2][0], 0, 0, 0);
            acc1[2][1] = __builtin_amdgcn_mfma_f32_16x16x32_bf16(a2, w1, acc1[2][1], 0, 0, 0);
            acc1[3][0] = __builtin_amdgcn_mfma_f32_16x16x32_bf16(a3, w0, acc1[3][0], 0, 0, 0);
            acc1[3][1] = __builtin_amdgcn_mfma_f32_16x16x32_bf16(a3, w1, acc1[3][1], 0, 0, 0);
            __builtin_amdgcn_s_setprio(0);
        }
        // bias + silu -> hs (bf16, swizzled). D layout: col=l&15, row=(l>>4)*4+reg
        #pragma unroll
        for (int rf = 0; rf < 4; ++rf) {
            #pragma unroll
            for (int cf = 0; cf < 2; ++cf) {
                int colb = (wc*32 + cf*16 + lr) * 2;
                float bb = cf ? b1c1 : b1c0;
                #pragma unroll
                for (int reg = 0; reg < 4; ++reg) {
                    int row = rf*16 + lq*4 + reg;
                    float sv = acc1[rf][cf][reg] + bb;
                    float hv = sv / (1.0f + __expf(-sv));
                    *(unsigned short*)((char*)hs + row*256 + (colb ^ ((row & 7) << 4))) = f2bf(hv);
                }
            }
        }
        asm volatile("s_waitcnt lgkmcnt(0)" ::: "memory");
        __builtin_amdgcn_s_barrier();          // hs ready; weight DMAs stay in flight

        #pragma unroll
        for (int r2 = 8; r2 < 12; ++r2) {
            short8 a0, a1, a2, a3;
            {
                const char* hb = (const char*)hs;
                int s2 = r2 - 8;
                a0 = *(const short8*)(hb + (0*16+lr)*256 + ((s2*64 + klq) ^ (((0*16+lr)&7) << 4)));
                a1 = *(const short8*)(hb + (1*16+lr)*256 + ((s2*64 + klq) ^ (((1*16+lr)&7) << 4)));
                a2 = *(const short8*)(hb + (2*16+lr)*256 + ((s2*64 + klq) ^ (((2*16+lr)&7) << 4)));
                a3 = *(const short8*)(hb + (3*16+lr)*256 + ((s2*64 + klq) ^ (((3*16+lr)&7) << 4)));
            }
            STAGE(c, r2 + 2);
            asm volatile("s_waitcnt vmcnt(4)" ::: "memory");
            const char* wb = (const char*)wbuf + (r2%3)*8192 + wc*2048 + l*16;
            short8 w0 = *(const short8*)wb;
            short8 w1 = *(const short8*)(wb + 1024);
            __builtin_amdgcn_s_setprio(1);
            yacc[0][0] = __builtin_amdgcn_mfma_f32_16x16x32_bf16(a0, w0, yacc[0][0], 0, 0, 0);
            yacc[0][1] = __builtin_amdgcn_mfma_f32_16x16x32_bf16(a0, w1, yacc[0][1], 0, 0, 0);
            yacc[1][0] = __builtin_amdgcn_mfma_f32_16x16x32_bf16(a1, w0, yacc[1][0], 0, 0, 0);
            yacc[1][1] = __builtin_amdgcn_mfma_f32_16x16x32_bf16(a1, w1, yacc[1][1], 0, 0, 0);
            yacc[2][0] = __builtin_amdgcn_mfma_f32_16x16x32_bf16(a2, w0, yacc[2][0], 0, 0, 0);
            yacc[2][1] = __builtin_amdgcn_mfma_f32_16x16x32_bf16(a2, w1, yacc[2][1], 0, 0, 0);
            yacc[3][0] = __builtin_amdgcn_mfma_f32_16x16x32_bf16(a3, w0, yacc[3][0], 0, 0, 0);
            yacc[3][1] = __builtin_amdgcn_mfma_f32_16x16x32_bf16(a3, w1, yacc[3][1], 0, 0, 0);
            __builtin_amdgcn_s_setprio(0);
        }
        if (c < 3) {   // hs reads done block-wide before next chunk overwrites
            asm volatile("s_waitcnt lgkmcnt(0)" ::: "memory");
            __builtin_amdgcn_s_barrier();
        }
    }

    // epilogue: y = yacc + b2 for valid rows
    float bo0 = b2s[wc*32 + lr], bo1 = b2s[wc*32 + 16 + lr];
    #pragma unroll
    for (int rf = 0; rf < 4; ++rf) {
        #pragma unroll
        for (int cf = 0; cf < 2; ++cf) {
            int col = wc*32 + cf*16 + lr;
            float bo = cf ? bo1 : bo0;
            #pragma unroll
            for (int reg = 0; reg < 4; ++reg) {
                int row = rf*16 + lq*4 + reg;
                if (row < nb)
                    y_out[(size_t)sb[row]*DOUT + col] = yacc[rf][cf][reg] + bo;
            }
        }
    }
}

extern "C" void kernel_launch(void* const* d_in, const int* in_sizes, int n_in,
                              void* d_out, int out_size, void* d_ws, size_t ws_size,
                              hipStream_t stream) {
    const int*   z  = (const int*)  d_in[0];
    const float* r  = (const float*)d_in[1];
    const float* x  = (const float*)d_in[2];
    const int*   t  = (const int*)  d_in[3];
    const float* W1 = (const float*)d_in[4];
    const float* b1 = (const float*)d_in[5];
    const float* W2 = (const float*)d_in[6];
    const float* b2 = (const float*)d_in[7];
    float* out = (float*)d_out;

    char* ws = (char*)d_ws;
    int*   cursors  = (int*)(ws);                 // 256 B
    int*   bond_ids = (int*)(ws + 256);           // 25*1408*4 = 140800 B
    short* x_bf     = (short*)(ws + 141312);      // 1 MB
    short* W1p      = (short*)(ws + 1189888);     // 6.25 MB
    short* W2p      = (short*)(ws + 7743488);     // 3.125 MB

    k_pre<<<PRE_BLK, 256, 0, stream>>>(z, x, t, W1, W2, out, x_bf, W1p, W2p, cursors);
    k_scatter<<<NBOND/256, 256, 0, stream>>>(z, r, t, out + OFF_V, out + OFF_Y, cursors, bond_ids);
    k_gemm<<<GBLK, 256, 0, stream>>>(x_bf, t, W1p, b1, W2p, b2, cursors, bond_ids, out + OFF_Y);
}